// Round 3
// baseline (44.778 us; speedup 1.0000x reference)
//
#include <hip/hip_runtime.h>
#include <math.h>

#define BLOCK 256
#define MAXT  64
#define FXSCALE 268435456.0   // 2^28 fixed-point scale for deterministic integer atomics

// Fused kernel: one thread per anchor TRIPLE (q, q+A/3, q+2A/3) of one batch b.
// Division-free assignment:
//   iou = n/(d-n), n=inter, d=area_a+area_t, is monotone in n/d =>
//   argmax via cross-mult n_t*d_best > n_best*d_t; max_iou>0.5 <=> 3*n_best>d_best.
// Cross-block reduction: per-block f32 tree reduce -> fixed-point int64 atomicAdd
// (order-independent => deterministic). Last-arriving block writes the outputs.
// acc[0]=bce_fx, acc[1]=sl1_fx, acc[2]=npos, acc[3]=arrival counter (memset to 0
// by kernel_launch each call).
__global__ void __launch_bounds__(BLOCK)
rpn_fused(const float* __restrict__ reg,
          const float* __restrict__ cls,
          const float* __restrict__ anchors,
          const float* __restrict__ targets,
          unsigned long long* __restrict__ acc,
          float* __restrict__ out,
          int A, int B, int T) {
    const int thirdA = A / 3;
    const int blocksPerB = thirdA / BLOCK;           // exact for this shape
    const int b = blockIdx.x / blocksPerB;
    const int q = (blockIdx.x - b * blocksPerB) * BLOCK + threadIdx.x;

    __shared__ float4 s_box[MAXT];
    __shared__ float  s_area[MAXT];
    if (threadIdx.x < T) {
        const float4 t4 = reinterpret_cast<const float4*>(targets)[b * T + threadIdx.x];
        s_box[threadIdx.x]  = t4;
        s_area[threadIdx.x] = (t4.z - t4.x) * (t4.w - t4.y);
    }
    __syncthreads();

    const int a0 = q, a1 = q + thirdA, a2 = q + 2 * thirdA;
    const float4 A0 = reinterpret_cast<const float4*>(anchors)[a0];
    const float4 A1 = reinterpret_cast<const float4*>(anchors)[a1];
    const float4 A2 = reinterpret_cast<const float4*>(anchors)[a2];
    const float sa0 = (A0.z - A0.x) * (A0.w - A0.y);
    const float sa1 = (A1.z - A1.x) * (A1.w - A1.y);
    const float sa2 = (A2.z - A2.x) * (A2.w - A2.y);

    float bn0 = 0.f, bd0 = 1.f, bn1 = 0.f, bd1 = 1.f, bn2 = 0.f, bd2 = 1.f;
    int bt0 = 0, bt1 = 0, bt2 = 0;

    #pragma unroll 4
    for (int t = 0; t < T; ++t) {
        const float4 tb = s_box[t];
        const float  st = s_area[t];
        {
            const float iw = fmaxf(fminf(tb.z, A0.z) - fmaxf(tb.x, A0.x), 0.f);
            const float ih = fmaxf(fminf(tb.w, A0.w) - fmaxf(tb.y, A0.y), 0.f);
            const float n = iw * ih, d = sa0 + st;
            if (n * bd0 > bn0 * d) { bn0 = n; bd0 = d; bt0 = t; }  // first-max
        }
        {
            const float iw = fmaxf(fminf(tb.z, A1.z) - fmaxf(tb.x, A1.x), 0.f);
            const float ih = fmaxf(fminf(tb.w, A1.w) - fmaxf(tb.y, A1.y), 0.f);
            const float n = iw * ih, d = sa1 + st;
            if (n * bd1 > bn1 * d) { bn1 = n; bd1 = d; bt1 = t; }
        }
        {
            const float iw = fmaxf(fminf(tb.z, A2.z) - fmaxf(tb.x, A2.x), 0.f);
            const float ih = fmaxf(fminf(tb.w, A2.w) - fmaxf(tb.y, A2.y), 0.f);
            const float n = iw * ih, d = sa2 + st;
            if (n * bd2 > bn2 * d) { bn2 = n; bd2 = d; bt2 = t; }
        }
    }

    const int base = b * A;
    const float c0 = cls[base + a0];
    const float c1 = cls[base + a1];
    const float c2 = cls[base + a2];
    const float pos0 = (3.f * bn0 > bd0) ? 1.f : 0.f;
    const float pos1 = (3.f * bn1 > bd1) ? 1.f : 0.f;
    const float pos2 = (3.f * bn2 > bd2) ? 1.f : 0.f;
    // stable softplus, matches jax.nn.softplus
    float bce  = (fmaxf(c0, 0.f) + log1pf(expf(-fabsf(c0)))) - c0 * pos0;
    bce       += (fmaxf(c1, 0.f) + log1pf(expf(-fabsf(c1)))) - c1 * pos1;
    bce       += (fmaxf(c2, 0.f) + log1pf(expf(-fabsf(c2)))) - c2 * pos2;
    float npos = pos0 + pos1 + pos2;
    float sl1  = 0.f;

    if (pos0 != 0.f) {
        const float4 r  = reinterpret_cast<const float4*>(reg)[base + a0];
        const float4 tb = s_box[bt0];
        float e, ae;
        e = r.x - (tb.x - A0.x); ae = fabsf(e); sl1 += (ae < 1.f) ? 0.5f * e * e : ae - 0.5f;
        e = r.y - (tb.y - A0.y); ae = fabsf(e); sl1 += (ae < 1.f) ? 0.5f * e * e : ae - 0.5f;
        e = r.z - (tb.z - A0.z); ae = fabsf(e); sl1 += (ae < 1.f) ? 0.5f * e * e : ae - 0.5f;
        e = r.w - (tb.w - A0.w); ae = fabsf(e); sl1 += (ae < 1.f) ? 0.5f * e * e : ae - 0.5f;
    }
    if (pos1 != 0.f) {
        const float4 r  = reinterpret_cast<const float4*>(reg)[base + a1];
        const float4 tb = s_box[bt1];
        float e, ae;
        e = r.x - (tb.x - A1.x); ae = fabsf(e); sl1 += (ae < 1.f) ? 0.5f * e * e : ae - 0.5f;
        e = r.y - (tb.y - A1.y); ae = fabsf(e); sl1 += (ae < 1.f) ? 0.5f * e * e : ae - 0.5f;
        e = r.z - (tb.z - A1.z); ae = fabsf(e); sl1 += (ae < 1.f) ? 0.5f * e * e : ae - 0.5f;
        e = r.w - (tb.w - A1.w); ae = fabsf(e); sl1 += (ae < 1.f) ? 0.5f * e * e : ae - 0.5f;
    }
    if (pos2 != 0.f) {
        const float4 r  = reinterpret_cast<const float4*>(reg)[base + a2];
        const float4 tb = s_box[bt2];
        float e, ae;
        e = r.x - (tb.x - A2.x); ae = fabsf(e); sl1 += (ae < 1.f) ? 0.5f * e * e : ae - 0.5f;
        e = r.y - (tb.y - A2.y); ae = fabsf(e); sl1 += (ae < 1.f) ? 0.5f * e * e : ae - 0.5f;
        e = r.z - (tb.z - A2.z); ae = fabsf(e); sl1 += (ae < 1.f) ? 0.5f * e * e : ae - 0.5f;
        e = r.w - (tb.w - A2.w); ae = fabsf(e); sl1 += (ae < 1.f) ? 0.5f * e * e : ae - 0.5f;
    }

    // deterministic block reduction: wave64 shuffle then cross-wave LDS
    for (int off = 32; off > 0; off >>= 1) {
        bce  += __shfl_down(bce,  off, 64);
        sl1  += __shfl_down(sl1,  off, 64);
        npos += __shfl_down(npos, off, 64);
    }
    __shared__ float w_bce[BLOCK / 64], w_sl1[BLOCK / 64], w_np[BLOCK / 64];
    __shared__ int s_last;
    const int lane = threadIdx.x & 63, wid = threadIdx.x >> 6;
    if (lane == 0) { w_bce[wid] = bce; w_sl1[wid] = sl1; w_np[wid] = npos; }
    __syncthreads();

    if (threadIdx.x == 0) {
        float tb_ = 0.f, ts_ = 0.f, tn_ = 0.f;
        for (int w = 0; w < BLOCK / 64; ++w) {
            tb_ += w_bce[w]; ts_ += w_sl1[w]; tn_ += w_np[w];
        }
        // fixed-point, order-independent accumulation
        atomicAdd(&acc[0], (unsigned long long)llrint((double)tb_ * FXSCALE));
        atomicAdd(&acc[1], (unsigned long long)llrint((double)ts_ * FXSCALE));
        atomicAdd(&acc[2], (unsigned long long)(long long)lrintf(tn_));
        __threadfence();
        const unsigned long long old = atomicAdd(&acc[3], 1ull);
        s_last = (old == (unsigned long long)(gridDim.x - 1)) ? 1 : 0;
    }
    __syncthreads();

    if (s_last && threadIdx.x == 0) {
        __threadfence();
        const double tb_ = (double)atomicAdd(&acc[0], 0ull) / FXSCALE;
        const double ts_ = (double)atomicAdd(&acc[1], 0ull) / FXSCALE;
        const double tn_ = (double)atomicAdd(&acc[2], 0ull);
        const double denom = tn_ > 1.0 ? tn_ : 1.0;
        const double reg_loss = (tn_ > 0.0) ? (ts_ / denom) : 0.0;
        out[0] = (float)(tb_ / (double)(B * A));   // cls_loss (mean BCE)
        out[1] = (float)(reg_loss * 0.25);         // reg_loss / 4
    }
}

extern "C" void kernel_launch(void* const* d_in, const int* in_sizes, int n_in,
                              void* d_out, int out_size, void* d_ws, size_t ws_size,
                              hipStream_t stream) {
    const float* reg     = (const float*)d_in[0];
    const float* cls     = (const float*)d_in[1];
    const float* anchors = (const float*)d_in[2];
    const float* targets = (const float*)d_in[3];
    float* out = (float*)d_out;

    const int A = in_sizes[2] / 4;          // anchors [A,4]
    const int B = in_sizes[1] / A;          // cls [B,A]
    const int T = in_sizes[3] / (B * 4);    // targets [B,T,4]

    unsigned long long* acc = (unsigned long long*)d_ws;
    // zero the 4 accumulator cells every call (graph-capturable memset node);
    // protects against the once-only 0xAA ws poison and leaves no cross-call state
    hipMemsetAsync(acc, 0, 4 * sizeof(unsigned long long), stream);

    const int nblk = (B * (A / 3)) / BLOCK; // 512 for this shape (2 blocks/CU, even)
    rpn_fused<<<nblk, BLOCK, 0, stream>>>(reg, cls, anchors, targets, acc, out, A, B, T);
}

// Round 4
// 23.392 us; speedup vs baseline: 1.9142x; 1.9142x over previous
//
#include <hip/hip_runtime.h>
#include <math.h>

#define BLOCK 256
#define MAXT  64

// Kernel 1: one thread per anchor PAIR (q, q + A/2) of one batch b.
// Division-free assignment:
//   iou = n/(d-n) with n=inter, d=area_a+area_t is monotone in n/d,
//   so argmax via cross-mult n_t*d_best > n_best*d_t (strict > == first-max),
//   and max_iou > 0.5 <=> 3*n_best > d_best.
// No global atomics: per-block partials (SoA) + tiny second kernel. Deterministic.
__global__ void __launch_bounds__(BLOCK)
rpn_main(const float* __restrict__ reg,
         const float* __restrict__ cls,
         const float* __restrict__ anchors,
         const float* __restrict__ targets,
         float* __restrict__ partials,   // SoA: [3][nblk]
         int A, int B, int T, int nblk) {
    const int halfA = A >> 1;
    const int blocksPerB = halfA / BLOCK;            // exact for this shape
    const int b = blockIdx.x / blocksPerB;
    const int q = (blockIdx.x - b * blocksPerB) * BLOCK + threadIdx.x;

    __shared__ float4 s_box[MAXT];
    if (threadIdx.x < T)
        s_box[threadIdx.x] = reinterpret_cast<const float4*>(targets)[b * T + threadIdx.x];
    __syncthreads();

    const int a0 = q, a1 = q + halfA;
    const float4 A0 = reinterpret_cast<const float4*>(anchors)[a0];
    const float4 A1 = reinterpret_cast<const float4*>(anchors)[a1];
    const float sa0 = (A0.z - A0.x) * (A0.w - A0.y);
    const float sa1 = (A1.z - A1.x) * (A1.w - A1.y);

    // hoist cls + softplus (independent of the loop -> ILP during LDS warmup)
    const int base = b * A;
    const float c0 = cls[base + a0];
    const float c1 = cls[base + a1];
    const float sp0 = fmaxf(c0, 0.f) + log1pf(expf(-fabsf(c0)));
    const float sp1 = fmaxf(c1, 0.f) + log1pf(expf(-fabsf(c1)));

    float bn0 = 0.f, bd0 = 1.f, bn1 = 0.f, bd1 = 1.f;
    int bt0 = 0, bt1 = 0;

    #pragma unroll 8
    for (int t = 0; t < T; ++t) {
        const float4 tb = s_box[t];                       // broadcast ds_read_b128
        const float st = (tb.z - tb.x) * (tb.w - tb.y);   // VALU instead of ds_read_b32
        {
            const float iw = fmaxf(fminf(tb.z, A0.z) - fmaxf(tb.x, A0.x), 0.f);
            const float ih = fmaxf(fminf(tb.w, A0.w) - fmaxf(tb.y, A0.y), 0.f);
            const float n = iw * ih, d = sa0 + st;
            if (n * bd0 > bn0 * d) { bn0 = n; bd0 = d; bt0 = t; }  // first-max
        }
        {
            const float iw = fmaxf(fminf(tb.z, A1.z) - fmaxf(tb.x, A1.x), 0.f);
            const float ih = fmaxf(fminf(tb.w, A1.w) - fmaxf(tb.y, A1.y), 0.f);
            const float n = iw * ih, d = sa1 + st;
            if (n * bd1 > bn1 * d) { bn1 = n; bd1 = d; bt1 = t; }
        }
    }

    const float pos0 = (3.f * bn0 > bd0) ? 1.f : 0.f;
    const float pos1 = (3.f * bn1 > bd1) ? 1.f : 0.f;
    float bce  = (sp0 - c0 * pos0) + (sp1 - c1 * pos1);
    float npos = pos0 + pos1;
    float sl1  = 0.f;

    if (pos0 != 0.f) {
        const float4 r  = reinterpret_cast<const float4*>(reg)[base + a0];
        const float4 tb = s_box[bt0];
        float e, ae;
        e = r.x - (tb.x - A0.x); ae = fabsf(e); sl1 += (ae < 1.f) ? 0.5f * e * e : ae - 0.5f;
        e = r.y - (tb.y - A0.y); ae = fabsf(e); sl1 += (ae < 1.f) ? 0.5f * e * e : ae - 0.5f;
        e = r.z - (tb.z - A0.z); ae = fabsf(e); sl1 += (ae < 1.f) ? 0.5f * e * e : ae - 0.5f;
        e = r.w - (tb.w - A0.w); ae = fabsf(e); sl1 += (ae < 1.f) ? 0.5f * e * e : ae - 0.5f;
    }
    if (pos1 != 0.f) {
        const float4 r  = reinterpret_cast<const float4*>(reg)[base + a1];
        const float4 tb = s_box[bt1];
        float e, ae;
        e = r.x - (tb.x - A1.x); ae = fabsf(e); sl1 += (ae < 1.f) ? 0.5f * e * e : ae - 0.5f;
        e = r.y - (tb.y - A1.y); ae = fabsf(e); sl1 += (ae < 1.f) ? 0.5f * e * e : ae - 0.5f;
        e = r.z - (tb.z - A1.z); ae = fabsf(e); sl1 += (ae < 1.f) ? 0.5f * e * e : ae - 0.5f;
        e = r.w - (tb.w - A1.w); ae = fabsf(e); sl1 += (ae < 1.f) ? 0.5f * e * e : ae - 0.5f;
    }

    // deterministic block reduction: wave64 shuffle then cross-wave LDS
    for (int off = 32; off > 0; off >>= 1) {
        bce  += __shfl_down(bce,  off, 64);
        sl1  += __shfl_down(sl1,  off, 64);
        npos += __shfl_down(npos, off, 64);
    }
    __shared__ float w_bce[BLOCK / 64], w_sl1[BLOCK / 64], w_np[BLOCK / 64];
    const int lane = threadIdx.x & 63, wid = threadIdx.x >> 6;
    if (lane == 0) { w_bce[wid] = bce; w_sl1[wid] = sl1; w_np[wid] = npos; }
    __syncthreads();
    if (threadIdx.x == 0) {
        float tb_ = 0.f, ts_ = 0.f, tn_ = 0.f;
        for (int w = 0; w < BLOCK / 64; ++w) {
            tb_ += w_bce[w]; ts_ += w_sl1[w]; tn_ += w_np[w];
        }
        partials[0 * nblk + blockIdx.x] = tb_;
        partials[1 * nblk + blockIdx.x] = ts_;
        partials[2 * nblk + blockIdx.x] = tn_;
    }
}

// Kernel 2: single block, double-precision deterministic final reduce.
__global__ void __launch_bounds__(256)
rpn_final(const float* __restrict__ partials, int nblk,
          float* __restrict__ out, int BA) {
    double b = 0.0, s = 0.0, n = 0.0;
    for (int i = threadIdx.x; i < nblk; i += 256) {
        b += (double)partials[0 * nblk + i];
        s += (double)partials[1 * nblk + i];
        n += (double)partials[2 * nblk + i];
    }
    __shared__ double sb[256], ss[256], sn[256];
    sb[threadIdx.x] = b; ss[threadIdx.x] = s; sn[threadIdx.x] = n;
    __syncthreads();
    for (int off = 128; off > 0; off >>= 1) {
        if (threadIdx.x < off) {
            sb[threadIdx.x] += sb[threadIdx.x + off];
            ss[threadIdx.x] += ss[threadIdx.x + off];
            sn[threadIdx.x] += sn[threadIdx.x + off];
        }
        __syncthreads();
    }
    if (threadIdx.x == 0) {
        const double npos = sn[0];
        const double denom = npos > 1.0 ? npos : 1.0;
        const double reg_loss = (npos > 0.0) ? (ss[0] / denom) : 0.0;
        out[0] = (float)(sb[0] / (double)BA);       // cls_loss (mean BCE)
        out[1] = (float)(reg_loss * 0.25);          // reg_loss / 4
    }
}

extern "C" void kernel_launch(void* const* d_in, const int* in_sizes, int n_in,
                              void* d_out, int out_size, void* d_ws, size_t ws_size,
                              hipStream_t stream) {
    const float* reg     = (const float*)d_in[0];
    const float* cls     = (const float*)d_in[1];
    const float* anchors = (const float*)d_in[2];
    const float* targets = (const float*)d_in[3];
    float* out = (float*)d_out;

    const int A = in_sizes[2] / 4;          // anchors [A,4]
    const int B = in_sizes[1] / A;          // cls [B,A]
    const int T = in_sizes[3] / (B * 4);    // targets [B,T,4]
    const int BA = B * A;
    const int nblk = (B * (A / 2)) / BLOCK; // 768 for this shape (3 blocks/CU)

    float* partials = (float*)d_ws;         // SoA [3][nblk], fully overwritten every call

    rpn_main<<<nblk, BLOCK, 0, stream>>>(reg, cls, anchors, targets,
                                         partials, A, B, T, nblk);
    rpn_final<<<1, 256, 0, stream>>>(partials, nblk, out, BA);
}